// Round 6
// baseline (95.080 us; speedup 1.0000x reference)
//
#include <hip/hip_runtime.h>

#define BATCH    8
#define T_LEN    4096
#define D_DIM    128
#define H_HEADS  4
#define O_DIM    32
#define E_EDGES  65536
#define N_NODES  (BATCH * T_LEN)      // 32768
#define NEG_SLOPE 0.2f

// ---------------------------------------------------------------------------
// Inline int64-vs-int32 layout detection (edge values < 4096, so int64 data
// has every odd 32-bit word zero). Done by wave 0 of each block.
// ---------------------------------------------------------------------------
__device__ __forceinline__ int detect_shift(const int* ei, int tidx, int* s_sh) {
    if (tidx < 64) {
        const int nz = (ei[2 * tidx + 1] != 0) ? 1 : 0;
        const unsigned long long b = __ballot(nz);
        if (tidx == 0) *s_sh = (b == 0ull) ? 1 : 0;
    }
    __syncthreads();
    return *s_sh;
}

// ---------------------------------------------------------------------------
// CSR build over the BASE graph (shared across batches).
// ---------------------------------------------------------------------------
__launch_bounds__(256)
__global__ void hist_kernel(const int* __restrict__ ei, int* __restrict__ deg) {
    __shared__ int s_sh;
    const int sh = detect_shift(ei, threadIdx.x, &s_sh);
    const int j = blockIdx.x * 256 + threadIdx.x;
    if (j >= E_EDGES) return;
    const int d = ei[(E_EDGES + j) << sh];
    atomicAdd(&deg[d], 1);
}

// exclusive scan of deg[4096] -> rowptr[4097], duplicate into cursor[4096]
__launch_bounds__(1024)
__global__ void scan_kernel(const int* __restrict__ deg,
                            int* __restrict__ rowptr, int* __restrict__ cursor) {
    __shared__ int wsum[16];
    const int tid  = threadIdx.x;
    const int w    = tid >> 6;
    const int lane = tid & 63;

    int v[4], s = 0;
    #pragma unroll
    for (int i = 0; i < 4; ++i) { v[i] = deg[tid * 4 + i]; s += v[i]; }

    // inclusive wave scan of s
    int inc = s;
    #pragma unroll
    for (int off = 1; off < 64; off <<= 1) {
        const int t = __shfl_up(inc, off);
        if (lane >= off) inc += t;
    }
    if (lane == 63) wsum[w] = inc;
    __syncthreads();
    if (w == 0) {
        const int t = (lane < 16) ? wsum[lane] : 0;
        int ti = t;
        #pragma unroll
        for (int off = 1; off < 16; off <<= 1) {
            const int u = __shfl_up(ti, off);
            if (lane >= off) ti += u;
        }
        if (lane < 16) wsum[lane] = ti - t;   // exclusive wave prefix
    }
    __syncthreads();

    int base = wsum[w] + (inc - s);           // exclusive prefix for this thread
    #pragma unroll
    for (int i = 0; i < 4; ++i) {
        rowptr[tid * 4 + i] = base;
        cursor[tid * 4 + i] = base;
        base += v[i];
    }
    if (tid == 1023) rowptr[4096] = base;
}

__launch_bounds__(256)
__global__ void fill_kernel(const int* __restrict__ ei,
                            int* __restrict__ cursor, int* __restrict__ col) {
    __shared__ int s_sh;
    const int sh = detect_shift(ei, threadIdx.x, &s_sh);
    const int j = blockIdx.x * 256 + threadIdx.x;
    if (j >= E_EDGES) return;
    const int s = ei[j << sh];
    const int d = ei[(E_EDGES + j) << sh];
    const int p = atomicAdd(&cursor[d], 1);
    col[p] = s;
}

// ---------------------------------------------------------------------------
// GEMM h = X*W (N x 128)(128 x 128), fp32 vector ALU. 1024 threads, 128 rows
// per block -> 256 blocks, 16 waves/CU. XCD-swizzled so the XCD that writes
// batch b's h/aS/aD slab is the one that reads it in gather (blockIdx%8=XCD).
// Xl padded to 132 cols (no bank broadcast conflict on the Xl[r][k] read).
// ---------------------------------------------------------------------------
__launch_bounds__(1024)
__global__ void gemm_att_kernel(const float* __restrict__ x,
                                const float* __restrict__ W,
                                const float* __restrict__ attS,
                                const float* __restrict__ attD,
                                float* __restrict__ h,
                                float* __restrict__ aS,
                                float* __restrict__ aD) {
    __shared__ float Wl[128][128];
    __shared__ float Xl[128][132];
    __shared__ float sAS[128];
    __shared__ float sAD[128];

    const int tid  = threadIdx.x;
    // batch = blk%8 (pins batch slab to one XCD), tile = blk/8
    const int row0 = (blockIdx.x & 7) * T_LEN + ((blockIdx.x >> 3) << 7);

    const float4* W4  = (const float4*)W;
    float4*       Wl4 = (float4*)&Wl[0][0];
    #pragma unroll
    for (int i = 0; i < 4; ++i)
        Wl4[tid + 1024 * i] = W4[tid + 1024 * i];

    const float4* X4 = (const float4*)(x + (size_t)row0 * 128);
    #pragma unroll
    for (int i = 0; i < 4; ++i) {
        const int idx = tid + 1024 * i;
        const int row = idx >> 5;
        const int c4  = idx & 31;
        *(float4*)&Xl[row][c4 * 4] = X4[idx];
    }

    if (tid < 128) { sAS[tid] = attS[tid]; sAD[tid] = attD[tid]; }
    __syncthreads();

    const int r  = tid >> 3;          // 0..127 row within tile
    const int cb = (tid & 7) * 16;    // 16 contiguous output cols

    float acc[16];
    #pragma unroll
    for (int i = 0; i < 16; ++i) acc[i] = 0.f;

    for (int k = 0; k < 128; ++k) {
        const float  xv = Xl[r][k];
        const float4 w0 = *(const float4*)&Wl[k][cb +  0];
        const float4 w1 = *(const float4*)&Wl[k][cb +  4];
        const float4 w2 = *(const float4*)&Wl[k][cb +  8];
        const float4 w3 = *(const float4*)&Wl[k][cb + 12];
        acc[ 0] += xv * w0.x; acc[ 1] += xv * w0.y; acc[ 2] += xv * w0.z; acc[ 3] += xv * w0.w;
        acc[ 4] += xv * w1.x; acc[ 5] += xv * w1.y; acc[ 6] += xv * w1.z; acc[ 7] += xv * w1.w;
        acc[ 8] += xv * w2.x; acc[ 9] += xv * w2.y; acc[10] += xv * w2.z; acc[11] += xv * w2.w;
        acc[12] += xv * w3.x; acc[13] += xv * w3.y; acc[14] += xv * w3.z; acc[15] += xv * w3.w;
    }

    const int row = row0 + r;
    float4* hp = (float4*)(h + (size_t)row * 128 + cb);
    hp[0] = make_float4(acc[0],  acc[1],  acc[2],  acc[3]);
    hp[1] = make_float4(acc[4],  acc[5],  acc[6],  acc[7]);
    hp[2] = make_float4(acc[8],  acc[9],  acc[10], acc[11]);
    hp[3] = make_float4(acc[12], acc[13], acc[14], acc[15]);

    float ps = 0.f, pd = 0.f;
    #pragma unroll
    for (int i = 0; i < 16; ++i) {
        ps += acc[i] * sAS[cb + i];
        pd += acc[i] * sAD[cb + i];
    }
    ps += __shfl_down(ps, 1);   // partner tid^1 holds the other 16 o's of this head
    pd += __shfl_down(pd, 1);
    if ((tid & 1) == 0) {
        const int hh = cb >> 5;
        aS[row * 4 + hh] = ps;
        aD[row * 4 + hh] = pd;
    }
}

// ---------------------------------------------------------------------------
// Gather-aggregate, 8-edge ILP + XCD batch pinning: blockIdx%8 = batch, so
// each XCD's L2 holds one batch's h slab (2 MB) + aS/aD (64 KB each).
// Wave = one node; lanes are 8 edge-slots x 8 channel-groups (16 ch each).
// Cross-slot shfl_xor (8,16,32) reduce at the end. Zero atomics.
// ---------------------------------------------------------------------------
__launch_bounds__(256)
__global__ void gather_kernel(const int* __restrict__ rowptr,
                              const int* __restrict__ col,
                              const float* __restrict__ h,
                              const float* __restrict__ aS,
                              const float* __restrict__ aD,
                              const float* __restrict__ bias,
                              float* __restrict__ out) {
    const int batch = blockIdx.x & 7;
    const int nib   = ((blockIdx.x >> 3) << 2) + (threadIdx.x >> 6); // node in batch
    const int lane  = threadIdx.x & 63;
    const int base  = batch * T_LEN;
    const int n     = base + nib;
    const int g     = lane >> 3;             // edge slot 0..7
    const int ci    = (lane & 7) * 16;       // first of 16 owned channels
    const int hh    = (lane & 7) >> 1;       // head of those channels

    const float ad  = aD[(size_t)n * 4 + hh];
    const int   beg = rowptr[nib];
    const int   end = rowptr[nib + 1];

    float4 A[4];
    #pragma unroll
    for (int i = 0; i < 4; ++i) A[i] = make_float4(0.f, 0.f, 0.f, 0.f);
    float dsum = 0.f;

    for (int k = beg + g; k < end; k += 8) {
        const int s = col[k] + base;
        float l = aS[(size_t)s * 4 + hh] + ad;
        l = (l > 0.f) ? l : NEG_SLOPE * l;
        const float w = __expf(l);
        dsum += w;
        const float4* hp = (const float4*)(h + (size_t)s * 128 + ci);
        #pragma unroll
        for (int i = 0; i < 4; ++i) {
            const float4 hv = hp[i];
            A[i].x += w * hv.x; A[i].y += w * hv.y;
            A[i].z += w * hv.z; A[i].w += w * hv.w;
        }
    }

    // self loop (slot 0 only, so it's counted once)
    if (g == 0) {
        float l = aS[(size_t)n * 4 + hh] + ad;
        l = (l > 0.f) ? l : NEG_SLOPE * l;
        const float w = __expf(l);
        dsum += w;
        const float4* hp = (const float4*)(h + (size_t)n * 128 + ci);
        #pragma unroll
        for (int i = 0; i < 4; ++i) {
            const float4 hv = hp[i];
            A[i].x += w * hv.x; A[i].y += w * hv.y;
            A[i].z += w * hv.z; A[i].w += w * hv.w;
        }
    }

    // reduce across the 8 edge slots (slot index = lane bits 3..5)
    #pragma unroll
    for (int i = 0; i < 4; ++i) {
        A[i].x += __shfl_xor(A[i].x, 8);  A[i].y += __shfl_xor(A[i].y, 8);
        A[i].z += __shfl_xor(A[i].z, 8);  A[i].w += __shfl_xor(A[i].w, 8);
        A[i].x += __shfl_xor(A[i].x, 16); A[i].y += __shfl_xor(A[i].y, 16);
        A[i].z += __shfl_xor(A[i].z, 16); A[i].w += __shfl_xor(A[i].w, 16);
        A[i].x += __shfl_xor(A[i].x, 32); A[i].y += __shfl_xor(A[i].y, 32);
        A[i].z += __shfl_xor(A[i].z, 32); A[i].w += __shfl_xor(A[i].w, 32);
    }
    dsum += __shfl_xor(dsum, 8);
    dsum += __shfl_xor(dsum, 16);
    dsum += __shfl_xor(dsum, 32);

    if (lane < 8) {
        const float inv = 1.0f / (dsum + 1e-16f);
        const float4* bp = (const float4*)(bias + ci);
        float* op = out + (size_t)n * 128 + ci;
        #pragma unroll
        for (int i = 0; i < 4; ++i) {
            const float4 b = bp[i];
            float4 o;
            o.x = A[i].x * inv + b.x; o.y = A[i].y * inv + b.y;
            o.z = A[i].z * inv + b.z; o.w = A[i].w * inv + b.w;
            ((float4*)op)[i] = o;
        }
    }
}

// ---------------------------------------------------------------------------
extern "C" void kernel_launch(void* const* d_in, const int* in_sizes, int n_in,
                              void* d_out, int out_size, void* d_ws, size_t ws_size,
                              hipStream_t stream) {
    const float* x    = (const float*)d_in[0];
    const int*   ei   = (const int*)  d_in[1];
    const float* W    = (const float*)d_in[2];
    const float* attS = (const float*)d_in[3];
    const float* attD = (const float*)d_in[4];
    const float* bias = (const float*)d_in[5];
    float* out = (float*)d_out;

    // workspace layout (4-byte units)
    float* ws     = (float*)d_ws;
    float* h      = ws;                                  // N*128
    float* aS     = h  + (size_t)N_NODES * 128;          // N*4
    float* aD     = aS + (size_t)N_NODES * 4;            // N*4
    int*   deg    = (int*)(aD + (size_t)N_NODES * 4);    // T
    int*   rowptr = deg    + T_LEN;                      // T+1
    int*   cursor = rowptr + T_LEN + 1;                  // T
    int*   col    = cursor + T_LEN;                      // E

    hipMemsetAsync(deg, 0, T_LEN * sizeof(int), stream);

    // CSR build (base graph)
    hist_kernel<<<E_EDGES / 256, 256, 0, stream>>>(ei, deg);
    scan_kernel<<<1, 1024, 0, stream>>>(deg, rowptr, cursor);
    fill_kernel<<<E_EDGES / 256, 256, 0, stream>>>(ei, cursor, col);

    // projection + attention logits (XCD-swizzled by batch)
    gemm_att_kernel<<<N_NODES / 128, 1024, 0, stream>>>(x, W, attS, attD, h, aS, aD);

    // gather-aggregate with fused softmax-normalize + bias (XCD batch pinning)
    gather_kernel<<<(N_NODES * 64) / 256, 256, 0, stream>>>(rowptr, col, h, aS, aD, bias, out);
}

// Round 7
// 75.997 us; speedup vs baseline: 1.2511x; 1.2511x over previous
//
#include <hip/hip_runtime.h>

#define BATCH    8
#define T_LEN    4096
#define D_DIM    128
#define H_HEADS  4
#define O_DIM    32
#define E_EDGES  65536
#define N_NODES  (BATCH * T_LEN)      // 32768
#define NEG_SLOPE 0.2f
#define SCAP     63                   // staged edges per node (excl. self loop)

// ---------------------------------------------------------------------------
// Inline int64-vs-int32 layout detection (edge values < 4096, so int64 data
// has every odd 32-bit word zero). Done by wave 0 of each block.
// ---------------------------------------------------------------------------
__device__ __forceinline__ int detect_shift(const int* ei, int tidx, int* s_sh) {
    if (tidx < 64) {
        const int nz = (ei[2 * tidx + 1] != 0) ? 1 : 0;
        const unsigned long long b = __ballot(nz);
        if (tidx == 0) *s_sh = (b == 0ull) ? 1 : 0;
    }
    __syncthreads();
    return *s_sh;
}

// ---------------------------------------------------------------------------
// CSR build over the BASE graph (shared across batches).
// ---------------------------------------------------------------------------
__launch_bounds__(256)
__global__ void hist_kernel(const int* __restrict__ ei, int* __restrict__ deg) {
    __shared__ int s_sh;
    const int sh = detect_shift(ei, threadIdx.x, &s_sh);
    const int j = blockIdx.x * 256 + threadIdx.x;
    if (j >= E_EDGES) return;
    const int d = ei[(E_EDGES + j) << sh];
    atomicAdd(&deg[d], 1);
}

// exclusive scan of deg[4096] -> rowptr[4097], duplicate into cursor[4096]
__launch_bounds__(1024)
__global__ void scan_kernel(const int* __restrict__ deg,
                            int* __restrict__ rowptr, int* __restrict__ cursor) {
    __shared__ int wsum[16];
    const int tid  = threadIdx.x;
    const int w    = tid >> 6;
    const int lane = tid & 63;

    int v[4], s = 0;
    #pragma unroll
    for (int i = 0; i < 4; ++i) { v[i] = deg[tid * 4 + i]; s += v[i]; }

    int inc = s;
    #pragma unroll
    for (int off = 1; off < 64; off <<= 1) {
        const int t = __shfl_up(inc, off);
        if (lane >= off) inc += t;
    }
    if (lane == 63) wsum[w] = inc;
    __syncthreads();
    if (w == 0) {
        const int t = (lane < 16) ? wsum[lane] : 0;
        int ti = t;
        #pragma unroll
        for (int off = 1; off < 16; off <<= 1) {
            const int u = __shfl_up(ti, off);
            if (lane >= off) ti += u;
        }
        if (lane < 16) wsum[lane] = ti - t;
    }
    __syncthreads();

    int base = wsum[w] + (inc - s);
    #pragma unroll
    for (int i = 0; i < 4; ++i) {
        rowptr[tid * 4 + i] = base;
        cursor[tid * 4 + i] = base;
        base += v[i];
    }
    if (tid == 1023) rowptr[4096] = base;
}

__launch_bounds__(256)
__global__ void fill_kernel(const int* __restrict__ ei,
                            int* __restrict__ cursor, int* __restrict__ col) {
    __shared__ int s_sh;
    const int sh = detect_shift(ei, threadIdx.x, &s_sh);
    const int j = blockIdx.x * 256 + threadIdx.x;
    if (j >= E_EDGES) return;
    const int s = ei[j << sh];
    const int d = ei[(E_EDGES + j) << sh];
    const int p = atomicAdd(&cursor[d], 1);
    col[p] = s;
}

// ---------------------------------------------------------------------------
// GEMM h = X*W (N x 128)(128 x 128), fp32 vector ALU, 4x16 register blocking.
// 256 threads, 128 rows/block, 256 blocks (XCD-swizzled: blk%8 = batch).
// Thread (cb=tid&7, rg=tid>>3) owns rows {rg+32*ri} x cols {cb*4+32*i + j}.
// Per k: 4 X + 16 W LDS floats for 64 FMAs (1.25 B/FMA -> ~0.67 GB total,
// ~10 us LDS-bound vs 33 us for the old 1x16 blocking).
// W reads: per instr 8 lanes x contiguous 16B chunks = 128B, conflict-free.
// Fused epilogue: per-node attention logits aS/aD [N,4] (head-packed float4).
// ---------------------------------------------------------------------------
__launch_bounds__(256)
__global__ void gemm_att_kernel(const float* __restrict__ x,
                                const float* __restrict__ W,
                                const float* __restrict__ attS,
                                const float* __restrict__ attD,
                                float* __restrict__ h,
                                float* __restrict__ aS,
                                float* __restrict__ aD) {
    __shared__ float Wl[128][132];
    __shared__ float Xl[128][132];
    __shared__ float sAS[128];
    __shared__ float sAD[128];

    const int tid  = threadIdx.x;
    // batch = blk%8 (XCD pin), tile = blk/8
    const int row0 = (blockIdx.x & 7) * T_LEN + ((blockIdx.x >> 3) << 7);

    // stage W and X into padded tiles (row stride 132 floats, 16B aligned)
    const float4* W4 = (const float4*)W;
    const float4* X4 = (const float4*)(x + (size_t)row0 * 128);
    #pragma unroll
    for (int i = 0; i < 16; ++i) {
        const int idx = tid + 256 * i;
        const int row = idx >> 5;
        const int c4  = idx & 31;
        *(float4*)&Wl[row][c4 * 4] = W4[idx];
        *(float4*)&Xl[row][c4 * 4] = X4[idx];
    }
    if (tid < 128) { sAS[tid] = attS[tid]; sAD[tid] = attD[tid]; }
    __syncthreads();

    const int cb = tid & 7;      // col group
    const int rg = tid >> 3;     // row group 0..31
    const int c0 = cb * 4;       // first col of chunk i is c0 + 32*i

    float4 acc[4][4];            // [ri][i]
    #pragma unroll
    for (int a = 0; a < 4; ++a)
        #pragma unroll
        for (int b = 0; b < 4; ++b)
            acc[a][b] = make_float4(0.f, 0.f, 0.f, 0.f);

    for (int k = 0; k < 128; ++k) {
        float xv[4];
        #pragma unroll
        for (int ri = 0; ri < 4; ++ri) xv[ri] = Xl[rg + 32 * ri][k];
        float4 wv[4];
        #pragma unroll
        for (int i = 0; i < 4; ++i) wv[i] = *(const float4*)&Wl[k][c0 + 32 * i];
        #pragma unroll
        for (int ri = 0; ri < 4; ++ri) {
            #pragma unroll
            for (int i = 0; i < 4; ++i) {
                acc[ri][i].x += xv[ri] * wv[i].x;
                acc[ri][i].y += xv[ri] * wv[i].y;
                acc[ri][i].z += xv[ri] * wv[i].z;
                acc[ri][i].w += xv[ri] * wv[i].w;
            }
        }
    }

    // store h + fused attention logits
    #pragma unroll
    for (int ri = 0; ri < 4; ++ri) {
        const int row = row0 + rg + 32 * ri;
        #pragma unroll
        for (int i = 0; i < 4; ++i)
            *(float4*)&h[(size_t)row * 128 + c0 + 32 * i] = acc[ri][i];

        // head i = col block 32*i; partial dot over this thread's 4 cols
        float4 ps = make_float4(0.f, 0.f, 0.f, 0.f);
        float4 pd = make_float4(0.f, 0.f, 0.f, 0.f);
        #pragma unroll
        for (int i = 0; i < 4; ++i) {
            const float* as = &sAS[32 * i + c0];
            const float* ad = &sAD[32 * i + c0];
            float s_ = acc[ri][i].x * as[0] + acc[ri][i].y * as[1]
                     + acc[ri][i].z * as[2] + acc[ri][i].w * as[3];
            float d_ = acc[ri][i].x * ad[0] + acc[ri][i].y * ad[1]
                     + acc[ri][i].z * ad[2] + acc[ri][i].w * ad[3];
            if (i == 0) { ps.x = s_; pd.x = d_; }
            if (i == 1) { ps.y = s_; pd.y = d_; }
            if (i == 2) { ps.z = s_; pd.z = d_; }
            if (i == 3) { ps.w = s_; pd.w = d_; }
        }
        // reduce over the 8 cb lanes (lane bits 0..2)
        #pragma unroll
        for (int off = 1; off < 8; off <<= 1) {
            ps.x += __shfl_xor(ps.x, off); ps.y += __shfl_xor(ps.y, off);
            ps.z += __shfl_xor(ps.z, off); ps.w += __shfl_xor(ps.w, off);
            pd.x += __shfl_xor(pd.x, off); pd.y += __shfl_xor(pd.y, off);
            pd.z += __shfl_xor(pd.z, off); pd.w += __shfl_xor(pd.w, off);
        }
        if (cb == 0) {
            *(float4*)&aS[(size_t)row * 4] = ps;
            *(float4*)&aD[(size_t)row * 4] = pd;
        }
    }
}

// ---------------------------------------------------------------------------
// Gather-aggregate v3: wave = one (batch,node). Phase 1 (parallel, one lane
// per edge incl. self-loop): stage s_j and w4_j = exp(lrelu(aS4[s]+aD4[n]))
// into LDS. Phase 2: channel loop with NO dependent chain: w from LDS
// (broadcast), h row via one coalesced 512B float2 load, 2 FMA. Each lane's
// dsum is complete (summed over all j) -> no cross-lane reduce. Zero atomics.
// ---------------------------------------------------------------------------
__launch_bounds__(256)
__global__ void gather_kernel(const int* __restrict__ rowptr,
                              const int* __restrict__ col,
                              const float* __restrict__ h,
                              const float* __restrict__ aS,
                              const float* __restrict__ aD,
                              const float* __restrict__ bias,
                              float* __restrict__ out) {
    __shared__ int   sbuf[4][SCAP + 1];
    __shared__ float wbuf[4][SCAP + 1][4];

    const int batch = blockIdx.x & 7;                 // XCD pin: batch slab in L2
    const int wv    = threadIdx.x >> 6;               // wave 0..3
    const int nib   = ((blockIdx.x >> 3) << 2) + wv;  // node within batch
    const int lane  = threadIdx.x & 63;
    const int base  = batch * T_LEN;
    const int n     = base + nib;
    const int hh    = lane >> 4;                      // head of channels 2*lane

    const int beg = rowptr[nib];
    const int end = rowptr[nib + 1];
    const int deg = end - beg;
    const int m   = (deg < SCAP) ? deg : SCAP;        // staged edge count

    // ---- phase 1: stage col + edge weights (one lane per staged entry)
    if (lane <= m) {
        const int s = (lane < m) ? (col[beg + lane] + base) : n;  // lane==m: self
        const float4 as4 = *(const float4*)(aS + (size_t)s * 4);
        const float4 ad4 = *(const float4*)(aD + (size_t)n * 4);
        float4 l;
        l.x = as4.x + ad4.x; l.x = (l.x > 0.f) ? l.x : NEG_SLOPE * l.x;
        l.y = as4.y + ad4.y; l.y = (l.y > 0.f) ? l.y : NEG_SLOPE * l.y;
        l.z = as4.z + ad4.z; l.z = (l.z > 0.f) ? l.z : NEG_SLOPE * l.z;
        l.w = as4.w + ad4.w; l.w = (l.w > 0.f) ? l.w : NEG_SLOPE * l.w;
        sbuf[wv][lane]    = s;
        wbuf[wv][lane][0] = __expf(l.x);
        wbuf[wv][lane][1] = __expf(l.y);
        wbuf[wv][lane][2] = __expf(l.z);
        wbuf[wv][lane][3] = __expf(l.w);
    }
    // wave-synchronous: same wave wrote, same wave reads (lgkmcnt handled)

    // ---- phase 2: channel accumulation
    float accx = 0.f, accy = 0.f, dsum = 0.f;
    const int nst = m + 1;
    #pragma unroll 4
    for (int j = 0; j < nst; ++j) {
        const int   s = sbuf[wv][j];
        const float w = wbuf[wv][j][hh];
        dsum += w;
        const float2 hv = *(const float2*)(h + (size_t)s * 128 + 2 * lane);
        accx += w * hv.x;
        accy += w * hv.y;
    }

    // rare overflow path (deg > SCAP): direct computation
    if (deg > SCAP) {
        const float adh = aD[(size_t)n * 4 + hh];
        for (int k = beg + SCAP; k < end; ++k) {
            const int s = col[k] + base;
            float l = aS[(size_t)s * 4 + hh] + adh;
            l = (l > 0.f) ? l : NEG_SLOPE * l;
            const float w = __expf(l);
            dsum += w;
            const float2 hv = *(const float2*)(h + (size_t)s * 128 + 2 * lane);
            accx += w * hv.x;
            accy += w * hv.y;
        }
    }

    const float inv = 1.0f / (dsum + 1e-16f);
    const float2 bv = *(const float2*)(bias + 2 * lane);
    float2 o;
    o.x = accx * inv + bv.x;
    o.y = accy * inv + bv.y;
    *(float2*)(out + (size_t)n * 128 + 2 * lane) = o;
}

// ---------------------------------------------------------------------------
extern "C" void kernel_launch(void* const* d_in, const int* in_sizes, int n_in,
                              void* d_out, int out_size, void* d_ws, size_t ws_size,
                              hipStream_t stream) {
    const float* x    = (const float*)d_in[0];
    const int*   ei   = (const int*)  d_in[1];
    const float* W    = (const float*)d_in[2];
    const float* attS = (const float*)d_in[3];
    const float* attD = (const float*)d_in[4];
    const float* bias = (const float*)d_in[5];
    float* out = (float*)d_out;

    // workspace layout (4-byte units)
    float* ws     = (float*)d_ws;
    float* h      = ws;                                  // N*128
    float* aS     = h  + (size_t)N_NODES * 128;          // N*4
    float* aD     = aS + (size_t)N_NODES * 4;            // N*4
    int*   deg    = (int*)(aD + (size_t)N_NODES * 4);    // T
    int*   rowptr = deg    + T_LEN;                      // T+1
    int*   cursor = rowptr + T_LEN + 1;                  // T
    int*   col    = cursor + T_LEN;                      // E

    hipMemsetAsync(deg, 0, T_LEN * sizeof(int), stream);

    // CSR build (base graph)
    hist_kernel<<<E_EDGES / 256, 256, 0, stream>>>(ei, deg);
    scan_kernel<<<1, 1024, 0, stream>>>(deg, rowptr, cursor);
    fill_kernel<<<E_EDGES / 256, 256, 0, stream>>>(ei, cursor, col);

    // projection + attention logits (XCD-swizzled by batch)
    gemm_att_kernel<<<N_NODES / 128, 256, 0, stream>>>(x, W, attS, attD, h, aS, aD);

    // gather-aggregate with fused softmax-normalize + bias (XCD batch pinning)
    gather_kernel<<<N_NODES / 4, 256, 0, stream>>>(rowptr, col, h, aS, aD, bias, out);
}

// Round 8
// 65.628 us; speedup vs baseline: 1.4488x; 1.1580x over previous
//
#include <hip/hip_runtime.h>

#define BATCH    8
#define T_LEN    4096
#define D_DIM    128
#define H_HEADS  4
#define O_DIM    32
#define E_EDGES  65536
#define N_NODES  (BATCH * T_LEN)      // 32768
#define NEG_SLOPE 0.2f
#define ELLCAP   64                   // slots per node (mean deg 16, sd 4 -> 12 sigma)
#define SPILLCAP 8192

// ---------------------------------------------------------------------------
// Inline int64-vs-int32 layout detection (edge values < 4096, so int64 data
// has every odd 32-bit word zero). Done by wave 0 of each block.
// ---------------------------------------------------------------------------
__device__ __forceinline__ int detect_shift(const int* ei, int tidx, int* s_sh) {
    if (tidx < 64) {
        const int nz = (ei[2 * tidx + 1] != 0) ? 1 : 0;
        const unsigned long long b = __ballot(nz);
        if (tidx == 0) *s_sh = (b == 0ull) ? 1 : 0;
    }
    __syncthreads();
    return *s_sh;
}

// ---------------------------------------------------------------------------
// Fused kernel: blocks [0,256) = GEMM h=X*W + attention logits (4x16 register
// blocking, LDS-BW optimized, XCD-swizzled blk%8=batch). Blocks [256,512) =
// ELL adjacency build (one atomic pass, no scan/fill needed). The edge pass
// hides under the GEMM instead of serializing after it.
// ---------------------------------------------------------------------------
__launch_bounds__(256)
__global__ void gemm_ell_kernel(const float* __restrict__ x,
                                const float* __restrict__ W,
                                const float* __restrict__ attS,
                                const float* __restrict__ attD,
                                const int* __restrict__ ei,
                                float* __restrict__ h,
                                float* __restrict__ aS,
                                float* __restrict__ aD,
                                int* __restrict__ cnt,
                                int* __restrict__ ell,
                                int* __restrict__ spill_cnt,
                                int2* __restrict__ spill) {
    __shared__ float Wl[128][132];
    __shared__ float Xl[128][132];
    __shared__ float sAS[128];
    __shared__ float sAD[128];
    __shared__ int   s_sh;

    const int tid = threadIdx.x;

    if (blockIdx.x >= 256) {
        // ---------------- ELL build branch ----------------
        const int sh = detect_shift(ei, tid, &s_sh);
        const int j  = (blockIdx.x - 256) * 256 + tid;   // exactly covers E_EDGES
        const int s  = ei[j << sh];
        const int d  = ei[(E_EDGES + j) << sh];
        const int p  = atomicAdd(&cnt[d], 1);
        if (p < ELLCAP) {
            ell[d * ELLCAP + p] = s;
        } else {
            const int q = atomicAdd(spill_cnt, 1);
            if (q < SPILLCAP) spill[q] = make_int2(s, d);
        }
        return;
    }

    // ---------------- GEMM branch (identical math to R7) ----------------
    // batch = blk%8 (XCD pin), tile = blk/8
    const int row0 = (blockIdx.x & 7) * T_LEN + ((blockIdx.x >> 3) << 7);

    const float4* W4 = (const float4*)W;
    const float4* X4 = (const float4*)(x + (size_t)row0 * 128);
    #pragma unroll
    for (int i = 0; i < 16; ++i) {
        const int idx = tid + 256 * i;
        const int row = idx >> 5;
        const int c4  = idx & 31;
        *(float4*)&Wl[row][c4 * 4] = W4[idx];
        *(float4*)&Xl[row][c4 * 4] = X4[idx];
    }
    if (tid < 128) { sAS[tid] = attS[tid]; sAD[tid] = attD[tid]; }
    __syncthreads();

    const int cb = tid & 7;      // col group
    const int rg = tid >> 3;     // row group 0..31
    const int c0 = cb * 4;       // first col of chunk i is c0 + 32*i

    float4 acc[4][4];            // [ri][i]
    #pragma unroll
    for (int a = 0; a < 4; ++a)
        #pragma unroll
        for (int b = 0; b < 4; ++b)
            acc[a][b] = make_float4(0.f, 0.f, 0.f, 0.f);

    for (int k = 0; k < 128; ++k) {
        float xv[4];
        #pragma unroll
        for (int ri = 0; ri < 4; ++ri) xv[ri] = Xl[rg + 32 * ri][k];
        float4 wv[4];
        #pragma unroll
        for (int i = 0; i < 4; ++i) wv[i] = *(const float4*)&Wl[k][c0 + 32 * i];
        #pragma unroll
        for (int ri = 0; ri < 4; ++ri) {
            #pragma unroll
            for (int i = 0; i < 4; ++i) {
                acc[ri][i].x += xv[ri] * wv[i].x;
                acc[ri][i].y += xv[ri] * wv[i].y;
                acc[ri][i].z += xv[ri] * wv[i].z;
                acc[ri][i].w += xv[ri] * wv[i].w;
            }
        }
    }

    #pragma unroll
    for (int ri = 0; ri < 4; ++ri) {
        const int row = row0 + rg + 32 * ri;
        #pragma unroll
        for (int i = 0; i < 4; ++i)
            *(float4*)&h[(size_t)row * 128 + c0 + 32 * i] = acc[ri][i];

        float4 ps = make_float4(0.f, 0.f, 0.f, 0.f);
        float4 pd = make_float4(0.f, 0.f, 0.f, 0.f);
        #pragma unroll
        for (int i = 0; i < 4; ++i) {
            const float* as = &sAS[32 * i + c0];
            const float* ad = &sAD[32 * i + c0];
            float s_ = acc[ri][i].x * as[0] + acc[ri][i].y * as[1]
                     + acc[ri][i].z * as[2] + acc[ri][i].w * as[3];
            float d_ = acc[ri][i].x * ad[0] + acc[ri][i].y * ad[1]
                     + acc[ri][i].z * ad[2] + acc[ri][i].w * ad[3];
            if (i == 0) { ps.x = s_; pd.x = d_; }
            if (i == 1) { ps.y = s_; pd.y = d_; }
            if (i == 2) { ps.z = s_; pd.z = d_; }
            if (i == 3) { ps.w = s_; pd.w = d_; }
        }
        #pragma unroll
        for (int off = 1; off < 8; off <<= 1) {
            ps.x += __shfl_xor(ps.x, off); ps.y += __shfl_xor(ps.y, off);
            ps.z += __shfl_xor(ps.z, off); ps.w += __shfl_xor(ps.w, off);
            pd.x += __shfl_xor(pd.x, off); pd.y += __shfl_xor(pd.y, off);
            pd.z += __shfl_xor(pd.z, off); pd.w += __shfl_xor(pd.w, off);
        }
        if (cb == 0) {
            *(float4*)&aS[(size_t)row * 4] = ps;
            *(float4*)&aD[(size_t)row * 4] = pd;
        }
    }
}

// ---------------------------------------------------------------------------
// Gather-aggregate: wave = one (batch,node). Phase 1 (parallel): stage ELL
// col + w4 = exp(lrelu(aS4[s]+aD4[n])) into LDS (one lane per edge; self-loop
// staged at slot m by lane m&63). Phase 2: dependence-free channel loop —
// w from LDS broadcast, coalesced 512B h row load, FMA. No cross-lane
// reduce needed, zero atomics. Spill fallback for the (never-hit) overflow.
// ---------------------------------------------------------------------------
__launch_bounds__(256)
__global__ void gather_kernel(const int* __restrict__ cnt,
                              const int* __restrict__ ell,
                              const int* __restrict__ spill_cnt,
                              const int2* __restrict__ spill,
                              const float* __restrict__ h,
                              const float* __restrict__ aS,
                              const float* __restrict__ aD,
                              const float* __restrict__ bias,
                              float* __restrict__ out) {
    __shared__ int   sbuf[4][ELLCAP + 1];
    __shared__ float wbuf[4][ELLCAP + 1][4];

    const int batch = blockIdx.x & 7;                 // XCD pin: batch slab in L2
    const int wv    = threadIdx.x >> 6;               // wave 0..3
    const int nib   = ((blockIdx.x >> 3) << 2) + wv;  // node within batch
    const int lane  = threadIdx.x & 63;
    const int base  = batch * T_LEN;
    const int n     = base + nib;
    const int hh    = lane >> 4;                      // head of channels 2*lane

    const int deg = cnt[nib];
    const int m   = (deg < ELLCAP) ? deg : ELLCAP;    // staged edge count

    const float4 ad4 = *(const float4*)(aD + (size_t)n * 4);

    // ---- phase 1: stage edges (lane j -> slot j)
    if (lane < m) {
        const int s = ell[nib * ELLCAP + lane] + base;
        const float4 as4 = *(const float4*)(aS + (size_t)s * 4);
        float4 l;
        l.x = as4.x + ad4.x; l.x = (l.x > 0.f) ? l.x : NEG_SLOPE * l.x;
        l.y = as4.y + ad4.y; l.y = (l.y > 0.f) ? l.y : NEG_SLOPE * l.y;
        l.z = as4.z + ad4.z; l.z = (l.z > 0.f) ? l.z : NEG_SLOPE * l.z;
        l.w = as4.w + ad4.w; l.w = (l.w > 0.f) ? l.w : NEG_SLOPE * l.w;
        sbuf[wv][lane]    = s;
        wbuf[wv][lane][0] = __expf(l.x);
        wbuf[wv][lane][1] = __expf(l.y);
        wbuf[wv][lane][2] = __expf(l.z);
        wbuf[wv][lane][3] = __expf(l.w);
    }
    // self loop -> slot m (lane m for m<64; lane 0 doubles up when m==64)
    if (lane == (m & 63)) {
        const float4 as4 = *(const float4*)(aS + (size_t)n * 4);
        float4 l;
        l.x = as4.x + ad4.x; l.x = (l.x > 0.f) ? l.x : NEG_SLOPE * l.x;
        l.y = as4.y + ad4.y; l.y = (l.y > 0.f) ? l.y : NEG_SLOPE * l.y;
        l.z = as4.z + ad4.z; l.z = (l.z > 0.f) ? l.z : NEG_SLOPE * l.z;
        l.w = as4.w + ad4.w; l.w = (l.w > 0.f) ? l.w : NEG_SLOPE * l.w;
        sbuf[wv][m]    = n;
        wbuf[wv][m][0] = __expf(l.x);
        wbuf[wv][m][1] = __expf(l.y);
        wbuf[wv][m][2] = __expf(l.z);
        wbuf[wv][m][3] = __expf(l.w);
    }
    // wave-synchronous: same wave wrote, same wave reads (DS ops in order)

    // ---- phase 2: channel accumulation (no dependent chain)
    float accx = 0.f, accy = 0.f, dsum = 0.f;
    const int nst = m + 1;
    #pragma unroll 4
    for (int j = 0; j < nst; ++j) {
        const int   s = sbuf[wv][j];
        const float w = wbuf[wv][j][hh];
        dsum += w;
        const float2 hv = *(const float2*)(h + (size_t)s * 128 + 2 * lane);
        accx += w * hv.x;
        accy += w * hv.y;
    }

    // ---- spill fallback (guaranteed-correct; count is 0 for this data)
    int sc = *spill_cnt;
    if (sc > 0) {
        if (sc > SPILLCAP) sc = SPILLCAP;
        const float adh = aD[(size_t)n * 4 + hh];
        for (int q = 0; q < sc; ++q) {
            const int2 e = spill[q];
            if (e.y == nib) {
                const int s = e.x + base;
                float l = aS[(size_t)s * 4 + hh] + adh;
                l = (l > 0.f) ? l : NEG_SLOPE * l;
                const float w = __expf(l);
                dsum += w;
                const float2 hv = *(const float2*)(h + (size_t)s * 128 + 2 * lane);
                accx += w * hv.x;
                accy += w * hv.y;
            }
        }
    }

    const float inv = 1.0f / (dsum + 1e-16f);
    const float2 bv = *(const float2*)(bias + 2 * lane);
    float2 o;
    o.x = accx * inv + bv.x;
    o.y = accy * inv + bv.y;
    *(float2*)(out + (size_t)n * 128 + 2 * lane) = o;
}

// ---------------------------------------------------------------------------
extern "C" void kernel_launch(void* const* d_in, const int* in_sizes, int n_in,
                              void* d_out, int out_size, void* d_ws, size_t ws_size,
                              hipStream_t stream) {
    const float* x    = (const float*)d_in[0];
    const int*   ei   = (const int*)  d_in[1];
    const float* W    = (const float*)d_in[2];
    const float* attS = (const float*)d_in[3];
    const float* attD = (const float*)d_in[4];
    const float* bias = (const float*)d_in[5];
    float* out = (float*)d_out;

    // workspace layout (4-byte units; base is 16B-aligned)
    float* ws        = (float*)d_ws;
    float* h         = ws;                                   // N*128
    float* aS        = h  + (size_t)N_NODES * 128;           // N*4
    float* aD        = aS + (size_t)N_NODES * 4;             // N*4
    int*   cnt       = (int*)(aD + (size_t)N_NODES * 4);     // T_LEN
    int*   spill_cnt = cnt + T_LEN;                          // 1
    int*   ell       = spill_cnt + 2;                        // T_LEN*ELLCAP (8B-aligned)
    int2*  spill     = (int2*)(ell + T_LEN * ELLCAP);        // SPILLCAP int2

    // zero cnt + spill_cnt in one memset
    hipMemsetAsync(cnt, 0, (T_LEN + 1) * sizeof(int), stream);

    // fused: GEMM+attention logits (blocks 0..255) || ELL build (blocks 256..511)
    gemm_ell_kernel<<<512, 256, 0, stream>>>(x, W, attS, attD, ei,
                                             h, aS, aD, cnt, ell, spill_cnt, spill);

    // gather-aggregate with fused softmax-normalize + bias
    gather_kernel<<<N_NODES / 4, 256, 0, stream>>>(cnt, ell, spill_cnt, spill,
                                                   h, aS, aD, bias, out);
}